// Round 2
// baseline (84.363 us; speedup 1.0000x reference)
//
#include <hip/hip_runtime.h>
#include <math.h>

#define NBLK 2048
#define NT 256
// NBLK * NT * 2 samples/thread = 1048576 = B exactly.
#define CNT_OFF (NBLK * 8)  // counter byte offset in d_ws, after float2[NBLK]

typedef float f32x2 __attribute__((ext_vector_type(2)));

__device__ __forceinline__ f32x2 relu2(f32x2 v) {
    f32x2 z = {0.0f, 0.0f};
    return __builtin_elementwise_max(v, z);
}

// z = (sigmoid(s) > n)  <=>  (1-n) > n*exp(-s)
__device__ __forceinline__ f32x2 zpair(f32x2 s, f32x2 n) {
    float ex = __expf(-s.x), ey = __expf(-s.y);
    f32x2 r;
    r.x = (1.0f - n.x > n.x * ex) ? 1.0f : 0.0f;
    r.y = (1.0f - n.y > n.y * ey) ? 1.0f : 0.0f;
    return r;
}

__device__ __forceinline__ float sp_f(float l) {  // softplus = max(l,0)+log1p(exp(-|l|))
    return fmaxf(l, 0.0f) + __logf(1.0f + __expf(-fabsf(l)));
}

__device__ __forceinline__ f32x2 bil(const f32x2* c, float z0, float z1, float p) {
    return c[0] + z0 * c[1] + z1 * c[2] + p * c[3];
}

// 2-layer MLPs, hidden=8, dout=2, packed pairwise.
__device__ __forceinline__ f32x2 mlp1(const float* w1, const float* b1,
                                      const float* w2, const float* b2, float x0) {
    const f32x2* w1v = (const f32x2*)w1;
    const f32x2* b1v = (const f32x2*)b1;
    const f32x2* w2v = (const f32x2*)w2;
    f32x2 acc = *(const f32x2*)b2;
    #pragma unroll
    for (int jp = 0; jp < 4; ++jp) {
        f32x2 h = relu2(b1v[jp] + x0 * w1v[jp]);
        acc += h.x * w2v[2 * jp] + h.y * w2v[2 * jp + 1];
    }
    return acc;
}

__device__ __forceinline__ f32x2 mlp2(const float* w1, const float* b1,
                                      const float* w2, const float* b2,
                                      float x0, float x1) {
    const f32x2* w1v = (const f32x2*)w1;
    const f32x2* b1v = (const f32x2*)b1;
    const f32x2* w2v = (const f32x2*)w2;
    f32x2 acc = *(const f32x2*)b2;
    #pragma unroll
    for (int jp = 0; jp < 4; ++jp) {
        f32x2 h = relu2(b1v[jp] + x0 * w1v[jp] + x1 * w1v[4 + jp]);
        acc += h.x * w2v[2 * jp] + h.y * w2v[2 * jp + 1];
    }
    return acc;
}

__device__ __forceinline__ f32x2 mlp3(const float* w1, const float* b1,
                                      const float* w2, const float* b2,
                                      float x0, float x1, float x2) {
    const f32x2* w1v = (const f32x2*)w1;
    const f32x2* b1v = (const f32x2*)b1;
    const f32x2* w2v = (const f32x2*)w2;
    f32x2 acc = *(const f32x2*)b2;
    #pragma unroll
    for (int jp = 0; jp < 4; ++jp) {
        f32x2 h = relu2(b1v[jp] + x0 * w1v[jp] + x1 * w1v[4 + jp] + x2 * w1v[8 + jp]);
        acc += h.x * w2v[2 * jp] + h.y * w2v[2 * jp + 1];
    }
    return acc;
}

__global__ __launch_bounds__(NT) void wake_fused(
    const float* __restrict__ y1, const float* __restrict__ y2,
    const float* __restrict__ n1, const float* __restrict__ n2,
    const float* __restrict__ n3, const float* __restrict__ n4,
    const float* __restrict__ i0w1, const float* __restrict__ i0b1,
    const float* __restrict__ i0w2, const float* __restrict__ i0b2,
    const float* __restrict__ i1w1, const float* __restrict__ i1b1,
    const float* __restrict__ i1w2, const float* __restrict__ i1b2,
    const float* __restrict__ i2w1, const float* __restrict__ i2b1,
    const float* __restrict__ i2w2, const float* __restrict__ i2b2,
    const float* __restrict__ i3w1, const float* __restrict__ i3b1,
    const float* __restrict__ i3w2, const float* __restrict__ i3b2,
    const float* __restrict__ g1w1, const float* __restrict__ g1b1,
    const float* __restrict__ g1w2, const float* __restrict__ g1b2,
    const float* __restrict__ g2w1, const float* __restrict__ g2b1,
    const float* __restrict__ g2w2, const float* __restrict__ g2b2,
    const float* __restrict__ g3w1, const float* __restrict__ g3b1,
    const float* __restrict__ g3w2, const float* __restrict__ g3b2,
    const float* __restrict__ g4w1, const float* __restrict__ g4b1,
    const float* __restrict__ g4w2, const float* __restrict__ g4b2,
    const float* __restrict__ g5w1, const float* __restrict__ g5b1,
    const float* __restrict__ g5w2, const float* __restrict__ g5b2,
    const float* __restrict__ g0w,
    float2* __restrict__ partials, unsigned* __restrict__ cnt,
    float* __restrict__ out)
{
    // Corner evals of the 5 binary-input MLPs, then bilinear coef pairs:
    // P0=(sig40,sig41)[z3], P1=(l30,l31)[z4], P2=(SP30,SP31)[z4],
    // P3=(l10,l11)[z2], P4=(SP10,SP11)[z2], P5=(muy2[z3], muy1[z1])
    __shared__ float lds_eval[5][4][2];
    __shared__ __align__(8) float lds_coef[6][4][2];  // [pair][term][elem]

    const int tid = threadIdx.x;
    const int g = blockIdx.x * NT + tid;

    // --- issue per-thread data loads early (2 samples: 2x8B + 4x16B = 80B) ---
    const f32x2 y1p = ((const f32x2*)y1)[g];
    const f32x2 y2p = ((const f32x2*)y2)[g];
    const float4 n1v = ((const float4*)n1)[g];
    const float4 n2v = ((const float4*)n2)[g];
    const float4 n3v = ((const float4*)n3)[g];
    const float4 n4v = ((const float4*)n4)[g];

    // --- stage 1: corner logits of the 5 binary-input MLPs (lanes 0..19) ---
    if (tid < 20) {
        const int m = tid >> 2, c = tid & 3;
        const float z0 = (float)(c & 1), z1f = (float)(c >> 1);
        const float *w1, *bb1, *w2, *bb2; int dout;
        switch (m) {
            case 0:  w1 = i3w1; bb1 = i3b1; w2 = i3w2; bb2 = i3b2; dout = 2; break;
            case 1:  w1 = g1w1; bb1 = g1b1; w2 = g1w2; bb2 = g1b2; dout = 2; break;
            case 2:  w1 = g2w1; bb1 = g2b1; w2 = g2w2; bb2 = g2b2; dout = 1; break;
            case 3:  w1 = g4w1; bb1 = g4b1; w2 = g4w2; bb2 = g4b2; dout = 2; break;
            default: w1 = g5w1; bb1 = g5b1; w2 = g5w2; bb2 = g5b2; dout = 1; break;
        }
        float o0 = bb2[0];
        float o1 = (dout == 2) ? bb2[1] : 0.0f;
        #pragma unroll
        for (int j = 0; j < 8; ++j) {
            float h = fmaxf(bb1[j] + z0 * w1[j] + z1f * w1[8 + j], 0.0f);
            o0 += h * w2[j * dout];
            if (dout == 2) o1 += h * w2[j * 2 + 1];
        }
        lds_eval[m][c][0] = o0;
        lds_eval[m][c][1] = o1;
    }
    __syncthreads();
    // --- stage 2: transform corners (id / sigmoid / softplus) -> coefs ---
    if (tid < 12) {
        const int pair = tid >> 1, elem = tid & 1;
        int m, k, tf;  // mlp index, output index, transform
        switch (tid) {
            case 0:  m = 0; k = 0; tf = 1; break;  // sig40
            case 1:  m = 0; k = 1; tf = 1; break;  // sig41
            case 2:  m = 1; k = 0; tf = 0; break;  // l30
            case 3:  m = 1; k = 1; tf = 0; break;  // l31
            case 4:  m = 1; k = 0; tf = 2; break;  // SP30
            case 5:  m = 1; k = 1; tf = 2; break;  // SP31
            case 6:  m = 3; k = 0; tf = 0; break;  // l10
            case 7:  m = 3; k = 1; tf = 0; break;  // l11
            case 8:  m = 3; k = 0; tf = 2; break;  // SP10
            case 9:  m = 3; k = 1; tf = 2; break;  // SP11
            case 10: m = 2; k = 0; tf = 0; break;  // muy2
            default: m = 4; k = 0; tf = 0; break;  // muy1
        }
        float f[4];
        #pragma unroll
        for (int c = 0; c < 4; ++c) {
            float x = lds_eval[m][c][k];
            if (tf == 1)      x = 1.0f / (1.0f + __expf(-x));
            else if (tf == 2) x = fmaxf(x, 0.0f) + log1pf(__expf(-fabsf(x)));
            f[c] = x;
        }
        lds_coef[pair][0][elem] = f[0];
        lds_coef[pair][1][elem] = f[1] - f[0];
        lds_coef[pair][2][elem] = f[2] - f[0];
        lds_coef[pair][3][elem] = f[3] - f[1] - f[2] + f[0];
    }
    __syncthreads();

    f32x2 C[6][4];
    #pragma unroll
    for (int pq = 0; pq < 24; ++pq)
        C[pq >> 2][pq & 3] = *(const f32x2*)&lds_coef[pq >> 2][pq & 3][0];
    const float L40 = g0w[0], L41 = g0w[1];

    const float Y1a[2] = {y1p.x, y1p.y};
    const float Y2a[2] = {y2p.x, y2p.y};
    f32x2 N1a[2], N2a[2], N3a[2], N4a[2];
    N1a[0].x = n1v.x; N1a[0].y = n1v.y; N1a[1].x = n1v.z; N1a[1].y = n1v.w;
    N2a[0].x = n2v.x; N2a[0].y = n2v.y; N2a[1].x = n2v.z; N2a[1].y = n2v.w;
    N3a[0].x = n3v.x; N3a[0].y = n3v.y; N3a[1].x = n3v.z; N3a[1].y = n3v.w;
    N4a[0].x = n4v.x; N4a[0].y = n4v.y; N4a[1].x = n4v.z; N4a[1].y = n4v.w;

    float lz = 0.0f;
    f32x2 lyv = {0.0f, 0.0f};
    #pragma unroll
    for (int s = 0; s < 2; ++s) {
        const float Y1 = Y1a[s], Y2 = Y2a[s];
        f32x2 s1 = mlp2(i0w1, i0b1, i0w2, i0b2, Y1, Y2);
        f32x2 z1 = zpair(s1, N1a[s]);
        f32x2 s2 = mlp3(i1w1, i1b1, i1w2, i1b2, Y2, z1.x, z1.y);
        f32x2 z2 = zpair(s2, N2a[s]);
        f32x2 s3 = mlp1(i2w1, i2b1, i2w2, i2b2, Y2);
        f32x2 z3 = zpair(s3, N3a[s]);
        const float p3 = z3.x * z3.y;
        f32x2 sig4 = bil(C[0], z3.x, z3.y, p3);
        f32x2 z4;
        z4.x = (sig4.x > N4a[s].x) ? 1.0f : 0.0f;
        z4.y = (sig4.y > N4a[s].y) ? 1.0f : 0.0f;
        const float p4 = z4.x * z4.y;
        f32x2 l3  = bil(C[1], z4.x, z4.y, p4);
        f32x2 SP3 = bil(C[2], z4.x, z4.y, p4);
        const float p2 = z2.x * z2.y;
        f32x2 l1  = bil(C[3], z2.x, z2.y, p2);
        f32x2 SP1 = bil(C[4], z2.x, z2.y, p2);
        const float p1 = z1.x * z1.y;
        f32x2 zA, zB, zP;
        zA.x = z3.x; zA.y = z1.x;
        zB.x = z3.y; zB.y = z1.y;
        zP.x = p3;   zP.y = p1;
        f32x2 mu = C[5][0] + zA * C[5][1] + zB * C[5][2] + zP * C[5][3];  // (muy2, muy1)
        f32x2 l2 = mlp1(g3w1, g3b1, g3w2, g3b2, Y2);
        f32x2 bsum = (SP1 - l1 * z1) + (SP3 - l3 * z3);
        f32x2 sp2;
        sp2.x = sp_f(l2.x); sp2.y = sp_f(l2.y);
        bsum += sp2 - l2 * z2;
        lz += bsum.x + bsum.y - (L40 * z4.x + L41 * z4.y);  // bce(l4,z4) variable part
        f32x2 d;
        d.x = Y2 - mu.x; d.y = Y1 - mu.y;
        lyv += d * d;  // *2 applied at the very end
    }

    // --- block reduction ---
    float lyf = lyv.x + lyv.y;
    #pragma unroll
    for (int off = 32; off > 0; off >>= 1) {
        lz  += __shfl_down(lz, off);
        lyf += __shfl_down(lyf, off);
    }
    __shared__ float2 wsum[NT / 64];
    __shared__ int sflag;
    const int lane = tid & 63, wid = tid >> 6;
    if (lane == 0) wsum[wid] = make_float2(lz, lyf);
    __syncthreads();
    if (tid == 0) {
        float a = 0.0f, b = 0.0f;
        #pragma unroll
        for (int w = 0; w < NT / 64; ++w) { a += wsum[w].x; b += wsum[w].y; }
        union { float2 f; unsigned long long u; } pk;
        pk.f = make_float2(a, b);
        __hip_atomic_store((unsigned long long*)&partials[blockIdx.x], pk.u,
                           __ATOMIC_RELEASE, __HIP_MEMORY_SCOPE_AGENT);
        unsigned v = __hip_atomic_fetch_add(cnt, 1u, __ATOMIC_ACQ_REL,
                                            __HIP_MEMORY_SCOPE_AGENT);
        sflag = (v == NBLK - 1);
    }
    __syncthreads();
    // --- last block folds all partials (fixed order -> deterministic) ---
    if (sflag) {
        float a = 0.0f, b = 0.0f;
        #pragma unroll
        for (int i = 0; i < NBLK / NT; ++i) {
            union { float2 f; unsigned long long u; } q;
            q.u = __hip_atomic_load((const unsigned long long*)&partials[tid + i * NT],
                                    __ATOMIC_ACQUIRE, __HIP_MEMORY_SCOPE_AGENT);
            a += q.f.x; b += q.f.y;
        }
        #pragma unroll
        for (int off = 32; off > 0; off >>= 1) {
            a += __shfl_down(a, off);
            b += __shfl_down(b, off);
        }
        if (lane == 0) wsum[wid] = make_float2(a, b);
        __syncthreads();
        if (tid == 0) {
            float sa = 0.0f, sb = 0.0f;
            #pragma unroll
            for (int w = 0; w < NT / 64; ++w) { sa += wsum[w].x; sb += wsum[w].y; }
            const float l40 = g0w[0], l41 = g0w[1];
            const float c4 = fmaxf(l40, 0.0f) + log1pf(expf(-fabsf(l40)))
                           + fmaxf(l41, 0.0f) + log1pf(expf(-fabsf(l41)));
            const float inv = 1.0f / 1048576.0f;
            const float loss_z = sa * inv + c4;
            const float loss_y = 2.0f * sb * inv + 0.4515827052894548f;
            out[0] = loss_z + loss_y;
            out[1] = loss_z;
            out[2] = loss_y;
        }
    }
}

extern "C" void kernel_launch(void* const* d_in, const int* in_sizes, int n_in,
                              void* d_out, int out_size, void* d_ws, size_t ws_size,
                              hipStream_t stream) {
    const float* p[43];
    for (int i = 0; i < 43; ++i) p[i] = (const float*)d_in[i];
    float2* partials = (float2*)d_ws;
    unsigned* cnt = (unsigned*)((char*)d_ws + CNT_OFF);
    hipMemsetAsync(cnt, 0, sizeof(unsigned), stream);
    wake_fused<<<NBLK, NT, 0, stream>>>(
        p[0], p[1], p[2], p[3], p[4], p[5],
        p[6], p[7], p[8], p[9],
        p[10], p[11], p[12], p[13],
        p[14], p[15], p[16], p[17],
        p[18], p[19], p[20], p[21],
        p[22], p[23], p[24], p[25],
        p[26], p[27], p[28], p[29],
        p[30], p[31], p[32], p[33],
        p[34], p[35], p[36], p[37],
        p[38], p[39], p[40], p[41],
        p[42], partials, cnt, (float*)d_out);
}

// Round 3
// 55.154 us; speedup vs baseline: 1.5296x; 1.5296x over previous
//
#include <hip/hip_runtime.h>
#include <math.h>

#define NB 1024
#define NT 256
// NB * NT * 4 samples/thread = 1048576 = B exactly.
#define CNT_OFF (NB * 8)  // counter byte offset in d_ws, after float2[NB]

__device__ __forceinline__ float zsel(float s, float n) {
    // (sigmoid(s) > n)  <=>  (1-n) > n*exp(-s)
    float e = __expf(-s);
    return (1.0f - n > n * e) ? 1.0f : 0.0f;
}
__device__ __forceinline__ float sp_f(float l) {  // softplus
    return fmaxf(l, 0.0f) + __logf(1.0f + __expf(-fabsf(l)));
}

__global__ __launch_bounds__(NT) void wake_fused(
    const float* __restrict__ y1, const float* __restrict__ y2,
    const float* __restrict__ n1, const float* __restrict__ n2,
    const float* __restrict__ n3, const float* __restrict__ n4,
    const float* __restrict__ i0w1, const float* __restrict__ i0b1,
    const float* __restrict__ i0w2, const float* __restrict__ i0b2,
    const float* __restrict__ i1w1, const float* __restrict__ i1b1,
    const float* __restrict__ i1w2, const float* __restrict__ i1b2,
    const float* __restrict__ i2w1, const float* __restrict__ i2b1,
    const float* __restrict__ i2w2, const float* __restrict__ i2b2,
    const float* __restrict__ i3w1, const float* __restrict__ i3b1,
    const float* __restrict__ i3w2, const float* __restrict__ i3b2,
    const float* __restrict__ g1w1, const float* __restrict__ g1b1,
    const float* __restrict__ g1w2, const float* __restrict__ g1b2,
    const float* __restrict__ g2w1, const float* __restrict__ g2b1,
    const float* __restrict__ g2w2, const float* __restrict__ g2b2,
    const float* __restrict__ g3w1, const float* __restrict__ g3b1,
    const float* __restrict__ g3w2, const float* __restrict__ g3b2,
    const float* __restrict__ g4w1, const float* __restrict__ g4b1,
    const float* __restrict__ g4w2, const float* __restrict__ g4b2,
    const float* __restrict__ g5w1, const float* __restrict__ g5b1,
    const float* __restrict__ g5w2, const float* __restrict__ g5b2,
    const float* __restrict__ g0w,
    float2* __restrict__ partials, unsigned* __restrict__ cnt,
    float* __restrict__ out)
{
    // Corner tables for the 5 binary-input MLPs -> bilinear coef pairs:
    // P0=(sig40,sig41)[z3] P1=(l30,l31)[z4] P2=(SP30,SP31)[z4]
    // P3=(l10,l11)[z2] P4=(SP10,SP11)[z2] P5=(muy2[z3], muy1[z1])
    __shared__ float lds_eval[5][4][2];
    __shared__ float lds_coef[6][4][2];  // [pair][term][elem]

    const int tid = threadIdx.x;
    const int g = blockIdx.x * NT + tid;

    // --- all per-thread data loads issued up front (10 x float4 = 160B) ---
    const float4 vy1  = reinterpret_cast<const float4*>(y1)[g];
    const float4 vy2  = reinterpret_cast<const float4*>(y2)[g];
    const float4 n1lo = reinterpret_cast<const float4*>(n1)[2*g];
    const float4 n1hi = reinterpret_cast<const float4*>(n1)[2*g+1];
    const float4 n2lo = reinterpret_cast<const float4*>(n2)[2*g];
    const float4 n2hi = reinterpret_cast<const float4*>(n2)[2*g+1];
    const float4 n3lo = reinterpret_cast<const float4*>(n3)[2*g];
    const float4 n3hi = reinterpret_cast<const float4*>(n3)[2*g+1];
    const float4 n4lo = reinterpret_cast<const float4*>(n4)[2*g];
    const float4 n4hi = reinterpret_cast<const float4*>(n4)[2*g+1];

    // --- stage 1: corner logits of the 5 binary-input MLPs (lanes 0..19) ---
    if (tid < 20) {
        const int m = tid >> 2, c = tid & 3;
        const float z0 = (float)(c & 1), z1f = (float)(c >> 1);
        const float *w1, *bb1, *w2, *bb2; int dout;
        switch (m) {
            case 0:  w1 = i3w1; bb1 = i3b1; w2 = i3w2; bb2 = i3b2; dout = 2; break;
            case 1:  w1 = g1w1; bb1 = g1b1; w2 = g1w2; bb2 = g1b2; dout = 2; break;
            case 2:  w1 = g2w1; bb1 = g2b1; w2 = g2w2; bb2 = g2b2; dout = 1; break;
            case 3:  w1 = g4w1; bb1 = g4b1; w2 = g4w2; bb2 = g4b2; dout = 2; break;
            default: w1 = g5w1; bb1 = g5b1; w2 = g5w2; bb2 = g5b2; dout = 1; break;
        }
        float o0 = bb2[0];
        float o1 = (dout == 2) ? bb2[1] : 0.0f;
        #pragma unroll
        for (int j = 0; j < 8; ++j) {
            float h = fmaxf(bb1[j] + z0 * w1[j] + z1f * w1[8 + j], 0.0f);
            o0 += h * w2[j * dout];
            if (dout == 2) o1 += h * w2[j * 2 + 1];
        }
        lds_eval[m][c][0] = o0;
        lds_eval[m][c][1] = o1;
    }
    __syncthreads();
    // --- stage 2: transform corners (id / sigmoid / softplus) -> coefs ---
    if (tid < 12) {
        const int pair = tid >> 1, elem = tid & 1;
        int m, k, tf;
        switch (tid) {
            case 0:  m = 0; k = 0; tf = 1; break;  // sig40
            case 1:  m = 0; k = 1; tf = 1; break;  // sig41
            case 2:  m = 1; k = 0; tf = 0; break;  // l30
            case 3:  m = 1; k = 1; tf = 0; break;  // l31
            case 4:  m = 1; k = 0; tf = 2; break;  // SP30
            case 5:  m = 1; k = 1; tf = 2; break;  // SP31
            case 6:  m = 3; k = 0; tf = 0; break;  // l10
            case 7:  m = 3; k = 1; tf = 0; break;  // l11
            case 8:  m = 3; k = 0; tf = 2; break;  // SP10
            case 9:  m = 3; k = 1; tf = 2; break;  // SP11
            case 10: m = 2; k = 0; tf = 0; break;  // muy2
            default: m = 4; k = 0; tf = 0; break;  // muy1
        }
        float f[4];
        #pragma unroll
        for (int c = 0; c < 4; ++c) {
            float x = lds_eval[m][c][k];
            if (tf == 1)      x = 1.0f / (1.0f + expf(-x));
            else if (tf == 2) x = fmaxf(x, 0.0f) + log1pf(expf(-fabsf(x)));
            f[c] = x;
        }
        lds_coef[pair][0][elem] = f[0];
        lds_coef[pair][1][elem] = f[1] - f[0];
        lds_coef[pair][2][elem] = f[2] - f[0];
        lds_coef[pair][3][elem] = f[3] - f[1] - f[2] + f[0];
    }
    __syncthreads();

    const float Y1[4] = {vy1.x, vy1.y, vy1.z, vy1.w};
    const float Y2[4] = {vy2.x, vy2.y, vy2.z, vy2.w};
    const float N1[8] = {n1lo.x, n1lo.y, n1lo.z, n1lo.w, n1hi.x, n1hi.y, n1hi.z, n1hi.w};
    const float N2[8] = {n2lo.x, n2lo.y, n2lo.z, n2lo.w, n2hi.x, n2hi.y, n2hi.z, n2hi.w};
    const float N3[8] = {n3lo.x, n3lo.y, n3lo.z, n3lo.w, n3hi.x, n3hi.y, n3hi.z, n3hi.w};
    const float N4[8] = {n4lo.x, n4lo.y, n4lo.z, n4lo.w, n4hi.x, n4hi.y, n4hi.z, n4hi.w};

    float z10[4], z11[4], z20[4], z21[4], z30[4], z31[4], z40[4], z41[4];

    // ---- Phase A: inf0([y1,y2]) -> z1, all 4 samples (weights live once) ----
    #pragma unroll
    for (int s = 0; s < 4; ++s) {
        float a0 = i0b2[0], a1 = i0b2[1];
        #pragma unroll
        for (int j = 0; j < 8; ++j) {
            float h = fmaxf(i0b1[j] + Y1[s] * i0w1[j] + Y2[s] * i0w1[8 + j], 0.0f);
            a0 += h * i0w2[2 * j]; a1 += h * i0w2[2 * j + 1];
        }
        z10[s] = zsel(a0, N1[2 * s]);
        z11[s] = zsel(a1, N1[2 * s + 1]);
    }
    // ---- Phase B: inf1([y2,z1]) -> z2 ----
    #pragma unroll
    for (int s = 0; s < 4; ++s) {
        float a0 = i1b2[0], a1 = i1b2[1];
        #pragma unroll
        for (int j = 0; j < 8; ++j) {
            float h = fmaxf(i1b1[j] + Y2[s] * i1w1[j] + z10[s] * i1w1[8 + j]
                            + z11[s] * i1w1[16 + j], 0.0f);
            a0 += h * i1w2[2 * j]; a1 += h * i1w2[2 * j + 1];
        }
        z20[s] = zsel(a0, N2[2 * s]);
        z21[s] = zsel(a1, N2[2 * s + 1]);
    }
    // ---- Phase C: inf2(y2) -> z3 ----
    #pragma unroll
    for (int s = 0; s < 4; ++s) {
        float a0 = i2b2[0], a1 = i2b2[1];
        #pragma unroll
        for (int j = 0; j < 8; ++j) {
            float h = fmaxf(i2b1[j] + Y2[s] * i2w1[j], 0.0f);
            a0 += h * i2w2[2 * j]; a1 += h * i2w2[2 * j + 1];
        }
        z30[s] = zsel(a0, N3[2 * s]);
        z31[s] = zsel(a1, N3[2 * s + 1]);
    }
    // ---- Phase D: z4 via tabulated sigmoid(inf3 logits) over z3 corners ----
    {
        const float c00 = lds_coef[0][0][0], c10 = lds_coef[0][1][0],
                    c20 = lds_coef[0][2][0], c30 = lds_coef[0][3][0];
        const float c01 = lds_coef[0][0][1], c11 = lds_coef[0][1][1],
                    c21 = lds_coef[0][2][1], c31 = lds_coef[0][3][1];
        #pragma unroll
        for (int s = 0; s < 4; ++s) {
            const float p3 = z30[s] * z31[s];
            const float sg0 = c00 + c10 * z30[s] + c20 * z31[s] + c30 * p3;
            const float sg1 = c01 + c11 * z30[s] + c21 * z31[s] + c31 * p3;
            z40[s] = (sg0 > N4[2 * s])     ? 1.0f : 0.0f;
            z41[s] = (sg1 > N4[2 * s + 1]) ? 1.0f : 0.0f;
        }
    }
    // ---- Phase E: g3(y2) -> l2 logits (continuous-input MLP) ----
    float l20[4], l21[4];
    #pragma unroll
    for (int s = 0; s < 4; ++s) {
        float a0 = g3b2[0], a1 = g3b2[1];
        #pragma unroll
        for (int j = 0; j < 8; ++j) {
            float h = fmaxf(g3b1[j] + Y2[s] * g3w1[j], 0.0f);
            a0 += h * g3w2[2 * j]; a1 += h * g3w2[2 * j + 1];
        }
        l20[s] = a0; l21[s] = a1;
    }
    // ---- Phase F: losses from tables ----
    float C[5][4][2];
    #pragma unroll
    for (int p = 0; p < 5; ++p) {
        #pragma unroll
        for (int t = 0; t < 4; ++t) {
            C[p][t][0] = lds_coef[p + 1][t][0];
            C[p][t][1] = lds_coef[p + 1][t][1];
        }
    }
    const float L40 = g0w[0], L41 = g0w[1];

    float lz = 0.0f, ly = 0.0f;
    #pragma unroll
    for (int s = 0; s < 4; ++s) {
        const float p1 = z10[s] * z11[s];
        const float p2 = z20[s] * z21[s];
        const float p3 = z30[s] * z31[s];
        const float p4 = z40[s] * z41[s];
        // l3 / SP3 over z4
        const float l3a  = C[0][0][0] + C[0][1][0] * z40[s] + C[0][2][0] * z41[s] + C[0][3][0] * p4;
        const float l3b  = C[0][0][1] + C[0][1][1] * z40[s] + C[0][2][1] * z41[s] + C[0][3][1] * p4;
        const float SP3a = C[1][0][0] + C[1][1][0] * z40[s] + C[1][2][0] * z41[s] + C[1][3][0] * p4;
        const float SP3b = C[1][0][1] + C[1][1][1] * z40[s] + C[1][2][1] * z41[s] + C[1][3][1] * p4;
        // l1 / SP1 over z2
        const float l1a  = C[2][0][0] + C[2][1][0] * z20[s] + C[2][2][0] * z21[s] + C[2][3][0] * p2;
        const float l1b  = C[2][0][1] + C[2][1][1] * z20[s] + C[2][2][1] * z21[s] + C[2][3][1] * p2;
        const float SP1a = C[3][0][0] + C[3][1][0] * z20[s] + C[3][2][0] * z21[s] + C[3][3][0] * p2;
        const float SP1b = C[3][0][1] + C[3][1][1] * z20[s] + C[3][2][1] * z21[s] + C[3][3][1] * p2;
        // muy2 over z3 (elem0), muy1 over z1 (elem1)
        const float mu2 = C[4][0][0] + C[4][1][0] * z30[s] + C[4][2][0] * z31[s] + C[4][3][0] * p3;
        const float mu1 = C[4][0][1] + C[4][1][1] * z10[s] + C[4][2][1] * z11[s] + C[4][3][1] * p1;

        lz += (SP1a - l1a * z10[s]) + (SP1b - l1b * z11[s])
            + (sp_f(l20[s]) - l20[s] * z20[s]) + (sp_f(l21[s]) - l21[s] * z21[s])
            + (SP3a - l3a * z30[s]) + (SP3b - l3b * z31[s])
            - (L40 * z40[s] + L41 * z41[s]);
        const float d1 = Y1[s] - mu1, d2 = Y2[s] - mu2;
        ly += d1 * d1 + d2 * d2;  // *2 applied at the end
    }

    // ---- block reduction -> one float2 partial per block ----
    #pragma unroll
    for (int off = 32; off > 0; off >>= 1) {
        lz += __shfl_down(lz, off);
        ly += __shfl_down(ly, off);
    }
    __shared__ float2 wsum[NT / 64];
    __shared__ int sflag;
    const int lane = tid & 63, wid = tid >> 6;
    if (lane == 0) wsum[wid] = make_float2(lz, ly);
    __syncthreads();
    if (tid == 0) {
        float a = 0.0f, b = 0.0f;
        #pragma unroll
        for (int w = 0; w < NT / 64; ++w) { a += wsum[w].x; b += wsum[w].y; }
        union { float2 f; unsigned long long u; } pk;
        pk.f = make_float2(a, b);
        __hip_atomic_store((unsigned long long*)&partials[blockIdx.x], pk.u,
                           __ATOMIC_RELEASE, __HIP_MEMORY_SCOPE_AGENT);
        unsigned v = __hip_atomic_fetch_add(cnt, 1u, __ATOMIC_ACQ_REL,
                                            __HIP_MEMORY_SCOPE_AGENT);
        sflag = (v == NB - 1);
    }
    __syncthreads();
    // ---- last block folds all partials (fixed order -> deterministic) ----
    if (sflag) {
        float a = 0.0f, b = 0.0f;
        #pragma unroll
        for (int i = 0; i < NB / NT; ++i) {
            union { float2 f; unsigned long long u; } q;
            q.u = __hip_atomic_load((const unsigned long long*)&partials[tid + i * NT],
                                    __ATOMIC_ACQUIRE, __HIP_MEMORY_SCOPE_AGENT);
            a += q.f.x; b += q.f.y;
        }
        #pragma unroll
        for (int off = 32; off > 0; off >>= 1) {
            a += __shfl_down(a, off);
            b += __shfl_down(b, off);
        }
        if (lane == 0) wsum[wid] = make_float2(a, b);
        __syncthreads();
        if (tid == 0) {
            float sa = 0.0f, sb = 0.0f;
            #pragma unroll
            for (int w = 0; w < NT / 64; ++w) { sa += wsum[w].x; sb += wsum[w].y; }
            const float l40 = g0w[0], l41 = g0w[1];
            const float c4 = fmaxf(l40, 0.0f) + log1pf(expf(-fabsf(l40)))
                           + fmaxf(l41, 0.0f) + log1pf(expf(-fabsf(l41)));
            const float inv = 1.0f / 1048576.0f;
            const float loss_z = sa * inv + c4;
            const float loss_y = 2.0f * sb * inv + 0.4515827052894548f;
            out[0] = loss_z + loss_y;
            out[1] = loss_z;
            out[2] = loss_y;
        }
    }
}

extern "C" void kernel_launch(void* const* d_in, const int* in_sizes, int n_in,
                              void* d_out, int out_size, void* d_ws, size_t ws_size,
                              hipStream_t stream) {
    const float* p[43];
    for (int i = 0; i < 43; ++i) p[i] = (const float*)d_in[i];
    float2* partials = (float2*)d_ws;
    unsigned* cnt = (unsigned*)((char*)d_ws + CNT_OFF);
    hipMemsetAsync(cnt, 0, sizeof(unsigned), stream);
    wake_fused<<<NB, NT, 0, stream>>>(
        p[0], p[1], p[2], p[3], p[4], p[5],
        p[6], p[7], p[8], p[9],
        p[10], p[11], p[12], p[13],
        p[14], p[15], p[16], p[17],
        p[18], p[19], p[20], p[21],
        p[22], p[23], p[24], p[25],
        p[26], p[27], p[28], p[29],
        p[30], p[31], p[32], p[33],
        p[34], p[35], p[36], p[37],
        p[38], p[39], p[40], p[41],
        p[42], partials, cnt, (float*)d_out);
}

// Round 4
// 25.574 us; speedup vs baseline: 3.2987x; 2.1566x over previous
//
#include <hip/hip_runtime.h>
#include <math.h>

#define NBLK 4096
#define NT 256
// NBLK * NT * 1 sample/thread = 1048576 = B exactly.
#define TBL_OFF (NBLK * 8)  // byte offset of coef table in d_ws (after float2[NBLK])

__device__ __forceinline__ float zsel(float s, float n) {
    // (sigmoid(s) > n)  <=>  (1-n) > n*exp(-s)
    float e = __expf(-s);
    return (1.0f - n > n * e) ? 1.0f : 0.0f;
}
__device__ __forceinline__ float sp_f(float l) {  // softplus
    return fmaxf(l, 0.0f) + __logf(1.0f + __expf(-fabsf(l)));
}

// ---------------- kernel A: build bilinear coefficient tables ----------------
// tbl[p][t][e], p in 0..5, t in 0..3 (1, z0, z1, z0*z1), e in 0..1:
// P0=(sig40,sig41)[z3] P1=(l30,l31)[z4] P2=(SP30,SP31)[z4]
// P3=(l10,l11)[z2] P4=(SP10,SP11)[z2] P5=(muy2[z3], muy1[z1])
__global__ __launch_bounds__(64) void make_tables(
    const float* __restrict__ i3w1, const float* __restrict__ i3b1,
    const float* __restrict__ i3w2, const float* __restrict__ i3b2,
    const float* __restrict__ g1w1, const float* __restrict__ g1b1,
    const float* __restrict__ g1w2, const float* __restrict__ g1b2,
    const float* __restrict__ g2w1, const float* __restrict__ g2b1,
    const float* __restrict__ g2w2, const float* __restrict__ g2b2,
    const float* __restrict__ g4w1, const float* __restrict__ g4b1,
    const float* __restrict__ g4w2, const float* __restrict__ g4b2,
    const float* __restrict__ g5w1, const float* __restrict__ g5b1,
    const float* __restrict__ g5w2, const float* __restrict__ g5b2,
    float* __restrict__ tbl)
{
    __shared__ float lds_eval[5][4][2];
    const int tid = threadIdx.x;
    if (tid < 20) {
        const int m = tid >> 2, c = tid & 3;
        const float z0 = (float)(c & 1), z1f = (float)(c >> 1);
        const float *w1, *bb1, *w2, *bb2; int dout;
        switch (m) {
            case 0:  w1 = i3w1; bb1 = i3b1; w2 = i3w2; bb2 = i3b2; dout = 2; break;
            case 1:  w1 = g1w1; bb1 = g1b1; w2 = g1w2; bb2 = g1b2; dout = 2; break;
            case 2:  w1 = g2w1; bb1 = g2b1; w2 = g2w2; bb2 = g2b2; dout = 1; break;
            case 3:  w1 = g4w1; bb1 = g4b1; w2 = g4w2; bb2 = g4b2; dout = 2; break;
            default: w1 = g5w1; bb1 = g5b1; w2 = g5w2; bb2 = g5b2; dout = 1; break;
        }
        float o0 = bb2[0];
        float o1 = (dout == 2) ? bb2[1] : 0.0f;
        #pragma unroll
        for (int j = 0; j < 8; ++j) {
            float h = fmaxf(bb1[j] + z0 * w1[j] + z1f * w1[8 + j], 0.0f);
            o0 += h * w2[j * dout];
            if (dout == 2) o1 += h * w2[j * 2 + 1];
        }
        lds_eval[m][c][0] = o0;
        lds_eval[m][c][1] = o1;
    }
    __syncthreads();
    if (tid < 12) {
        const int pair = tid >> 1, elem = tid & 1;
        int m, k, tf;
        switch (tid) {
            case 0:  m = 0; k = 0; tf = 1; break;  // sig40
            case 1:  m = 0; k = 1; tf = 1; break;  // sig41
            case 2:  m = 1; k = 0; tf = 0; break;  // l30
            case 3:  m = 1; k = 1; tf = 0; break;  // l31
            case 4:  m = 1; k = 0; tf = 2; break;  // SP30
            case 5:  m = 1; k = 1; tf = 2; break;  // SP31
            case 6:  m = 3; k = 0; tf = 0; break;  // l10
            case 7:  m = 3; k = 1; tf = 0; break;  // l11
            case 8:  m = 3; k = 0; tf = 2; break;  // SP10
            case 9:  m = 3; k = 1; tf = 2; break;  // SP11
            case 10: m = 2; k = 0; tf = 0; break;  // muy2
            default: m = 4; k = 0; tf = 0; break;  // muy1
        }
        float f[4];
        #pragma unroll
        for (int c = 0; c < 4; ++c) {
            float x = lds_eval[m][c][k];
            if (tf == 1)      x = 1.0f / (1.0f + expf(-x));
            else if (tf == 2) x = fmaxf(x, 0.0f) + log1pf(expf(-fabsf(x)));
            f[c] = x;
        }
        tbl[(pair * 4 + 0) * 2 + elem] = f[0];
        tbl[(pair * 4 + 1) * 2 + elem] = f[1] - f[0];
        tbl[(pair * 4 + 2) * 2 + elem] = f[2] - f[0];
        tbl[(pair * 4 + 3) * 2 + elem] = f[3] - f[1] - f[2] + f[0];
    }
}

// ---------------- kernel B: main, 1 sample/thread, no prologue ----------------
__global__ __launch_bounds__(NT, 6) void wake_main(
    const float* __restrict__ y1, const float* __restrict__ y2,
    const float* __restrict__ n1, const float* __restrict__ n2,
    const float* __restrict__ n3, const float* __restrict__ n4,
    const float* __restrict__ i0w1, const float* __restrict__ i0b1,
    const float* __restrict__ i0w2, const float* __restrict__ i0b2,
    const float* __restrict__ i1w1, const float* __restrict__ i1b1,
    const float* __restrict__ i1w2, const float* __restrict__ i1b2,
    const float* __restrict__ i2w1, const float* __restrict__ i2b1,
    const float* __restrict__ i2w2, const float* __restrict__ i2b2,
    const float* __restrict__ g3w1, const float* __restrict__ g3b1,
    const float* __restrict__ g3w2, const float* __restrict__ g3b2,
    const float* __restrict__ g0w,
    const float* __restrict__ tbl,
    float2* __restrict__ partials)
{
    const int tid = threadIdx.x;
    const int g = blockIdx.x * NT + tid;

    // per-thread data: 40 B in 6 coalesced loads, issued up front
    const float Y1 = y1[g];
    const float Y2 = y2[g];
    const float2 N1 = reinterpret_cast<const float2*>(n1)[g];
    const float2 N2 = reinterpret_cast<const float2*>(n2)[g];
    const float2 N3 = reinterpret_cast<const float2*>(n3)[g];
    const float2 N4 = reinterpret_cast<const float2*>(n4)[g];

    // inf0([y1,y2]) -> z1
    float a0 = i0b2[0], a1 = i0b2[1];
    #pragma unroll
    for (int j = 0; j < 8; ++j) {
        float h = fmaxf(i0b1[j] + Y1 * i0w1[j] + Y2 * i0w1[8 + j], 0.0f);
        a0 += h * i0w2[2 * j]; a1 += h * i0w2[2 * j + 1];
    }
    const float z10 = zsel(a0, N1.x);
    const float z11 = zsel(a1, N1.y);

    // inf1([y2,z1]) -> z2
    float b0 = i1b2[0], b1v = i1b2[1];
    #pragma unroll
    for (int j = 0; j < 8; ++j) {
        float h = fmaxf(i1b1[j] + Y2 * i1w1[j] + z10 * i1w1[8 + j]
                        + z11 * i1w1[16 + j], 0.0f);
        b0 += h * i1w2[2 * j]; b1v += h * i1w2[2 * j + 1];
    }
    const float z20 = zsel(b0, N2.x);
    const float z21 = zsel(b1v, N2.y);

    // inf2(y2) -> z3
    float c0 = i2b2[0], c1 = i2b2[1];
    #pragma unroll
    for (int j = 0; j < 8; ++j) {
        float h = fmaxf(i2b1[j] + Y2 * i2w1[j], 0.0f);
        c0 += h * i2w2[2 * j]; c1 += h * i2w2[2 * j + 1];
    }
    const float z30 = zsel(c0, N3.x);
    const float z31 = zsel(c1, N3.y);

    // z4 via tabulated sigmoid over z3 corners
    const float p3 = z30 * z31;
    const float sg0 = tbl[0] + tbl[2] * z30 + tbl[4] * z31 + tbl[6] * p3;
    const float sg1 = tbl[1] + tbl[3] * z30 + tbl[5] * z31 + tbl[7] * p3;
    const float z40 = (sg0 > N4.x) ? 1.0f : 0.0f;
    const float z41 = (sg1 > N4.y) ? 1.0f : 0.0f;
    const float p4 = z40 * z41;

    // g3(y2) -> l2 (continuous-input MLP)
    float l20 = g3b2[0], l21 = g3b2[1];
    #pragma unroll
    for (int j = 0; j < 8; ++j) {
        float h = fmaxf(g3b1[j] + Y2 * g3w1[j], 0.0f);
        l20 += h * g3w2[2 * j]; l21 += h * g3w2[2 * j + 1];
    }

    // table losses
    const float l3a  = tbl[8]  + tbl[10] * z40 + tbl[12] * z41 + tbl[14] * p4;
    const float l3b  = tbl[9]  + tbl[11] * z40 + tbl[13] * z41 + tbl[15] * p4;
    const float SP3a = tbl[16] + tbl[18] * z40 + tbl[20] * z41 + tbl[22] * p4;
    const float SP3b = tbl[17] + tbl[19] * z40 + tbl[21] * z41 + tbl[23] * p4;
    const float p2 = z20 * z21;
    const float l1a  = tbl[24] + tbl[26] * z20 + tbl[28] * z21 + tbl[30] * p2;
    const float l1b  = tbl[25] + tbl[27] * z20 + tbl[29] * z21 + tbl[31] * p2;
    const float SP1a = tbl[32] + tbl[34] * z20 + tbl[36] * z21 + tbl[38] * p2;
    const float SP1b = tbl[33] + tbl[35] * z20 + tbl[37] * z21 + tbl[39] * p2;
    const float mu2  = tbl[40] + tbl[42] * z30 + tbl[44] * z31 + tbl[46] * p3;
    const float p1 = z10 * z11;
    const float mu1  = tbl[41] + tbl[43] * z10 + tbl[45] * z11 + tbl[47] * p1;
    const float L40 = g0w[0], L41 = g0w[1];

    float lz = (SP1a - l1a * z10) + (SP1b - l1b * z11)
             + (sp_f(l20) - l20 * z20) + (sp_f(l21) - l21 * z21)
             + (SP3a - l3a * z30) + (SP3b - l3b * z31)
             - (L40 * z40 + L41 * z41);
    const float d1 = Y1 - mu1, d2 = Y2 - mu2;
    float ly = d1 * d1 + d2 * d2;  // *2 applied in the reduce kernel

    // block reduction -> one float2 partial per block
    #pragma unroll
    for (int off = 32; off > 0; off >>= 1) {
        lz += __shfl_down(lz, off);
        ly += __shfl_down(ly, off);
    }
    __shared__ float2 wsum[NT / 64];
    const int lane = tid & 63, wid = tid >> 6;
    if (lane == 0) wsum[wid] = make_float2(lz, ly);
    __syncthreads();
    if (tid == 0) {
        float a = 0.0f, b = 0.0f;
        #pragma unroll
        for (int w = 0; w < NT / 64; ++w) { a += wsum[w].x; b += wsum[w].y; }
        partials[blockIdx.x] = make_float2(a, b);
    }
}

// ---------------- kernel C: final reduce ----------------
__global__ __launch_bounds__(256) void wake_reduce(
    const float2* __restrict__ partials, const float* __restrict__ g0w,
    float* __restrict__ out)
{
    const int tid = threadIdx.x;
    float lz = 0.0f, ly = 0.0f;
    #pragma unroll
    for (int i = 0; i < NBLK / 256; ++i) {
        float2 p = partials[tid + i * 256];
        lz += p.x; ly += p.y;
    }
    #pragma unroll
    for (int off = 32; off > 0; off >>= 1) {
        lz += __shfl_down(lz, off);
        ly += __shfl_down(ly, off);
    }
    __shared__ float2 wsum[4];
    const int lane = tid & 63, wid = tid >> 6;
    if (lane == 0) wsum[wid] = make_float2(lz, ly);
    __syncthreads();
    if (tid == 0) {
        float a = 0.0f, b = 0.0f;
        #pragma unroll
        for (int w = 0; w < 4; ++w) { a += wsum[w].x; b += wsum[w].y; }
        const float l40 = g0w[0], l41 = g0w[1];
        const float c4 = fmaxf(l40, 0.0f) + log1pf(expf(-fabsf(l40)))
                       + fmaxf(l41, 0.0f) + log1pf(expf(-fabsf(l41)));
        const float inv = 1.0f / 1048576.0f;
        const float loss_z = a * inv + c4;
        const float loss_y = 2.0f * b * inv + 0.4515827052894548f;
        out[0] = loss_z + loss_y;
        out[1] = loss_z;
        out[2] = loss_y;
    }
}

extern "C" void kernel_launch(void* const* d_in, const int* in_sizes, int n_in,
                              void* d_out, int out_size, void* d_ws, size_t ws_size,
                              hipStream_t stream) {
    const float* p[43];
    for (int i = 0; i < 43; ++i) p[i] = (const float*)d_in[i];
    float2* partials = (float2*)d_ws;
    float* tbl = (float*)((char*)d_ws + TBL_OFF);

    // binary-input MLP weights: inf3=18..21, g1=22..25, g2=26..29, g4=34..37, g5=38..41
    make_tables<<<1, 64, 0, stream>>>(
        p[18], p[19], p[20], p[21],
        p[22], p[23], p[24], p[25],
        p[26], p[27], p[28], p[29],
        p[34], p[35], p[36], p[37],
        p[38], p[39], p[40], p[41],
        tbl);
    wake_main<<<NBLK, NT, 0, stream>>>(
        p[0], p[1], p[2], p[3], p[4], p[5],
        p[6], p[7], p[8], p[9],
        p[10], p[11], p[12], p[13],
        p[14], p[15], p[16], p[17],
        p[30], p[31], p[32], p[33],
        p[42], tbl, partials);
    wake_reduce<<<1, 256, 0, stream>>>(partials, p[42], (float*)d_out);
}